// Round 1
// baseline (651.161 us; speedup 1.0000x reference)
//
#include <hip/hip_runtime.h>
#include <math.h>

#define Gn 16000
#define Bn 4096
#define Ln 64
#define Sn 20000

// ---------- device math helpers ----------

__device__ __forceinline__ float softplus_precise(float z) {
    // stable: max(z,0) + log1p(exp(-|z|))
    return fmaxf(z, 0.0f) + log1pf(__expf(-fabsf(z)));
}

// lgamma for z > 0, branchless: shift by 8 then Stirling with 1/(12w) term.
// abs error ~1e-6 over our range.
__device__ __forceinline__ float lgamma_pos(float z) {
    float p = z * (z + 1.f) * (z + 2.f) * (z + 3.f)
                * (z + 4.f) * (z + 5.f) * (z + 6.f) * (z + 7.f);
    float w = z + 8.f;
    float lw = __logf(w);
    return (w - 0.5f) * lw - w + 0.9189385332046727f
           + __fdividef(1.0f, 12.0f * w) - __logf(p);
}

// ---------- precompute kernels ----------

// Per-gene: rhatT [65][Gn] (l-major), lsp/lsn [Gn]
__global__ void prep_genes(const float* __restrict__ W,
                           const float* __restrict__ px_o,
                           const float* __restrict__ eta,
                           const float* __restrict__ beta,
                           float* __restrict__ rhatT,
                           float* __restrict__ lsp,
                           float* __restrict__ lsn) {
    int g = blockIdx.x * 256 + threadIdx.x;
    if (g >= Gn) return;
    float bsp = softplus_precise(beta[g]);
    #pragma unroll 4
    for (int l = 0; l < Ln; l++) {
        rhatT[l * Gn + g] = bsp * softplus_precise(W[g * Ln + l]);
    }
    rhatT[Ln * Gn + g] = softplus_precise(eta[g]);
    float o = px_o[g];
    lsp[g] = -softplus_precise(-o);   // log_sigmoid(o)
    lsn[g] = -softplus_precise(o);    // log_sigmoid(-o)
}

// Per-spot: vT [65][Bn] (l-major) = softplus(V[l, ind_x[b]])
__global__ void prep_spots(const float* __restrict__ V,
                           const int* __restrict__ ind_x,
                           float* __restrict__ vT) {
    int idx = blockIdx.x * 256 + threadIdx.x;   // 65*4096 total, exact
    int l = idx >> 12;
    int b = idx & (Bn - 1);
    int s = ind_x[b];
    vT[idx] = softplus_precise(V[l * Sn + s]);
}

// Scalar outputs: out[Bn] = 0.0, out[Bn+1] = sum(0.5*log(2pi) + 0.5*eta^2)
__global__ void prior_kernel(const float* __restrict__ eta, float* __restrict__ out) {
    int tid = threadIdx.x;
    float s = 0.f;
    for (int g = tid; g < Gn; g += 256) {
        float e = eta[g];
        s += 0.9189385332046727f + 0.5f * e * e;
    }
    #pragma unroll
    for (int off = 32; off; off >>= 1) s += __shfl_xor(s, off, 64);
    __shared__ float red[4];
    if ((tid & 63) == 0) red[tid >> 6] = s;
    __syncthreads();
    if (tid == 0) {
        out[Bn]     = 0.0f;
        out[Bn + 1] = red[0] + red[1] + red[2] + red[3];
    }
}

// ---------- main kernel: 64x64 output tile per block, 4x4 per thread ----------

__global__ __launch_bounds__(256) void main_kernel(
    const int*   __restrict__ x,
    const float* __restrict__ rhatT,
    const float* __restrict__ vT,
    const float* __restrict__ lsp,
    const float* __restrict__ lsn,
    float*       __restrict__ out) {
    __shared__ float rh[65][64];     // [l][gene]
    __shared__ float vv[65][64];     // [l][row]
    __shared__ float lfact[128];     // lgamma(x+1), x in [0,100)

    const int tid = threadIdx.x;
    const int g0 = blockIdx.x * 64;
    const int b0 = blockIdx.y * 64;

    if (tid < 100) lfact[tid] = lgamma_pos((float)tid + 1.0f);

    for (int idx = tid; idx < 65 * 64; idx += 256) {
        int l = idx >> 6, j = idx & 63;
        rh[l][j] = rhatT[l * Gn + g0 + j];
        vv[l][j] = vT[l * Bn + b0 + j];
    }

    const int tx = tid & 15;         // gene quad index
    const int ty = tid >> 4;         // row quad index
    const int gg = g0 + tx * 4;
    const int bb = b0 + ty * 4;

    // prefetch x tile (4 rows x 4 genes) and per-gene constants
    int4 xv[4];
    #pragma unroll
    for (int i = 0; i < 4; i++)
        xv[i] = *(const int4*)(x + (bb + i) * Gn + gg);
    const float4 lspv = *(const float4*)(lsp + gg);
    const float4 lsnv = *(const float4*)(lsn + gg);

    float acc[4][4];
    #pragma unroll
    for (int i = 0; i < 4; i++)
        #pragma unroll
        for (int k = 0; k < 4; k++) acc[i][k] = 0.f;

    __syncthreads();

    #pragma unroll 5
    for (int l = 0; l < 65; l++) {
        const float4 a = *(const float4*)&rh[l][tx * 4];
        const float4 b = *(const float4*)&vv[l][ty * 4];
        const float av[4] = {a.x, a.y, a.z, a.w};
        const float bv[4] = {b.x, b.y, b.z, b.w};
        #pragma unroll
        for (int i = 0; i < 4; i++)
            #pragma unroll
            for (int k = 0; k < 4; k++)
                acc[i][k] = fmaf(bv[i], av[k], acc[i][k]);
    }

    // epilogue: NB log-likelihood per element, row partial sums
    const float lspA[4] = {lspv.x, lspv.y, lspv.z, lspv.w};
    const float lsnA[4] = {lsnv.x, lsnv.y, lsnv.z, lsnv.w};
    float rowsum[4];
    #pragma unroll
    for (int i = 0; i < 4; i++) {
        const int xi4[4] = {xv[i].x, xv[i].y, xv[i].z, xv[i].w};
        float rs = 0.f;
        #pragma unroll
        for (int k = 0; k < 4; k++) {
            const float r  = acc[i][k];
            const int   xi = xi4[k];
            const float xf = (float)xi;
            const float s  = r + xf;
            // lgamma(x+r) - lgamma(r) via shift-by-8 Stirling; constants cancel
            float pr = r, px = s;
            #pragma unroll
            for (int j = 1; j < 8; j++) {
                pr *= (r + (float)j);
                px *= (s + (float)j);
            }
            const float wr = r + 8.f, wx = s + 8.f;
            const float lnq  = __logf(__fdividef(px, pr));
            const float lnwx = __logf(wx);
            const float lnwr = __logf(wr);
            // 1/(12wx) - 1/(12wr) = -xf/(12*wx*wr)
            float diff = (wx - 0.5f) * lnwx - (wr - 0.5f) * lnwr - xf
                       - 0.0833333333f * __fdividef(xf, wx * wr) - lnq;
            float term = diff - lfact[xi] + xf * lspA[k] + r * lsnA[k];
            rs += term;
        }
        rowsum[i] = rs;
    }

    // reduce across the 16 gene-lanes sharing each row, then atomic into out
    #pragma unroll
    for (int i = 0; i < 4; i++) {
        float v = rowsum[i];
        v += __shfl_xor(v, 1, 64);
        v += __shfl_xor(v, 2, 64);
        v += __shfl_xor(v, 4, 64);
        v += __shfl_xor(v, 8, 64);
        if (tx == 0) atomicAdd(&out[bb + i], -v);
    }
}

// ---------- launch ----------

extern "C" void kernel_launch(void* const* d_in, const int* in_sizes, int n_in,
                              void* d_out, int out_size, void* d_ws, size_t ws_size,
                              hipStream_t stream) {
    const int*   x     = (const int*)d_in[0];
    // d_in[1] = y (unused by the reference)
    const int*   ind_x = (const int*)d_in[2];
    const float* W     = (const float*)d_in[3];
    const float* px_o  = (const float*)d_in[4];
    const float* eta   = (const float*)d_in[5];
    const float* V     = (const float*)d_in[6];
    const float* beta  = (const float*)d_in[7];
    float* out = (float*)d_out;

    // workspace layout (floats): rhatT [65*Gn] | vT [65*Bn] | lsp [Gn] | lsn [Gn]
    float* rhatT = (float*)d_ws;
    float* vT    = rhatT + 65 * Gn;
    float* lsp   = vT + 65 * Bn;
    float* lsn   = lsp + Gn;

    // loss accumulators must start at zero (d_out is poisoned each call)
    hipMemsetAsync(d_out, 0, Bn * sizeof(float), stream);

    prep_genes<<<(Gn + 255) / 256, 256, 0, stream>>>(W, px_o, eta, beta, rhatT, lsp, lsn);
    prep_spots<<<(65 * Bn) / 256, 256, 0, stream>>>(V, ind_x, vT);
    prior_kernel<<<1, 256, 0, stream>>>(eta, out);

    dim3 grid(Gn / 64, Bn / 64);   // 250 x 64
    main_kernel<<<grid, 256, 0, stream>>>(x, rhatT, vT, lsp, lsn, out);
}

// Round 3
// 480.103 us; speedup vs baseline: 1.3563x; 1.3563x over previous
//
#include <hip/hip_runtime.h>
#include <hip/hip_bf16.h>
#include <math.h>

#define Gn 16000
#define Bn 4096
#define Ln 64
#define Sn 20000

typedef __attribute__((ext_vector_type(8))) short bf16x8;   // 8 bf16 = 4 VGPRs
typedef __attribute__((ext_vector_type(4))) float f32x4;    // MFMA C/D

// ---------- device math helpers ----------

__device__ __forceinline__ float softplus_precise(float z) {
    return fmaxf(z, 0.0f) + log1pf(__expf(-fabsf(z)));
}

// accurate lgamma for z>0 (shift-8 Stirling), used only for the 100-entry table
__device__ __forceinline__ float lgamma_pos8(float z) {
    float p = z * (z + 1.f) * (z + 2.f) * (z + 3.f)
                * (z + 4.f) * (z + 5.f) * (z + 6.f) * (z + 7.f);
    float w = z + 8.f;
    return (w - 0.5f) * __logf(w) - w + 0.9189385332046727f
           + __fdividef(1.0f, 12.0f * w) - __logf(p);
}

__device__ __forceinline__ unsigned short f2bf(float f) {
    union { float f; unsigned int u; } v; v.f = f;
    unsigned int r = v.u + 0x7fff + ((v.u >> 16) & 1);   // RNE
    return (unsigned short)(r >> 16);
}

// ---------- precompute kernels ----------

// One thread per (g,l): rhB [Gn][64] bf16. Threads idx<Gn also do eps/lsp/lsn.
__global__ void prep_genes(const float* __restrict__ W,
                           const float* __restrict__ px_o,
                           const float* __restrict__ eta,
                           const float* __restrict__ beta,
                           unsigned short* __restrict__ rhB,
                           float* __restrict__ lsp,
                           float* __restrict__ lsn,
                           float* __restrict__ eps) {
    int idx = blockIdx.x * 256 + threadIdx.x;   // Gn*64 total, exact
    int g = idx >> 6;
    float bsp = softplus_precise(beta[g]);
    rhB[idx] = f2bf(bsp * softplus_precise(W[idx]));   // W row-major [G][L]
    if (idx < Gn) {
        eps[idx] = softplus_precise(eta[idx]);
        float o = px_o[idx];
        lsp[idx] = -softplus_precise(-o);   // log_sigmoid(o)
        lsn[idx] = -softplus_precise(o);    // log_sigmoid(-o)
    }
}

// Per-spot: vBg [Bn][64] bf16 (l inner), v64 [Bn] f32 (the l=64 row, kept fp32)
__global__ void prep_spots(const float* __restrict__ V,
                           const int* __restrict__ ind_x,
                           unsigned short* __restrict__ vBg,
                           float* __restrict__ v64) {
    int idx = blockIdx.x * 256 + threadIdx.x;   // Bn*64 total, exact
    int b = idx >> 6, l = idx & 63;
    int s = ind_x[b];
    vBg[idx] = f2bf(softplus_precise(V[l * Sn + s]));
    if (idx < Bn) {
        int s2 = ind_x[idx];
        v64[idx] = softplus_precise(V[Ln * Sn + s2]);
    }
}

// Scalar outputs
__global__ void prior_kernel(const float* __restrict__ eta, float* __restrict__ out) {
    int tid = threadIdx.x;
    float s = 0.f;
    for (int g = tid; g < Gn; g += 256) {
        float e = eta[g];
        s += 0.9189385332046727f + 0.5f * e * e;
    }
    #pragma unroll
    for (int off = 32; off; off >>= 1) s += __shfl_xor(s, off, 64);
    __shared__ float red[4];
    if ((tid & 63) == 0) red[tid >> 6] = s;
    __syncthreads();
    if (tid == 0) {
        out[Bn]     = 0.0f;
        out[Bn + 1] = red[0] + red[1] + red[2] + red[3];
    }
}

// ---------- main kernel: 64x64 tile per block, MFMA dot + slim NB epilogue ----------

__global__ __launch_bounds__(256) void main_kernel(
    const int*            __restrict__ x,
    const unsigned short* __restrict__ rhB,
    const unsigned short* __restrict__ vBg,
    const float*          __restrict__ v64,
    const float*          __restrict__ lspg,
    const float*          __restrict__ lsng,
    const float*          __restrict__ epsg,
    float*                __restrict__ out) {
    __shared__ __align__(16) unsigned short sA[64][72];   // v tile [b][l], pad->2-way free
    __shared__ __align__(16) unsigned short sB[64][72];   // rh tile [g][l]
    __shared__ float sv64[64];
    __shared__ float sLsp[64], sLsn[64], sEps[64];
    __shared__ float lfact[100];

    const int tid = threadIdx.x;
    const int g0 = blockIdx.x * 64;
    const int b0 = blockIdx.y * 64;

    {   // staging: FULL 64x64 tile = 8192B each; 256 thr x 16B x 2 row-passes
        int row = tid >> 3;          // 0..31
        int c   = (tid & 7) * 8;     // 0..56 step 8 (shorts)
        *(uint4*)&sA[row][c]      = *(const uint4*)&vBg[(b0 + row) * 64 + c];
        *(uint4*)&sA[row + 32][c] = *(const uint4*)&vBg[(b0 + row + 32) * 64 + c];
        *(uint4*)&sB[row][c]      = *(const uint4*)&rhB[(g0 + row) * 64 + c];
        *(uint4*)&sB[row + 32][c] = *(const uint4*)&rhB[(g0 + row + 32) * 64 + c];
    }
    if (tid < 64) {
        sv64[tid] = v64[b0 + tid];
        sLsp[tid] = lspg[g0 + tid];
        sLsn[tid] = lsng[g0 + tid];
        sEps[tid] = epsg[g0 + tid];
    }
    if (tid < 100) lfact[tid] = lgamma_pos8((float)tid + 1.0f);

    const int wave = tid >> 6, lane = tid & 63;
    const int quad = lane >> 4, ln = lane & 15;
    const int mrow  = wave * 16 + ln;              // A-fragment m index
    const int brow0 = b0 + wave * 16 + quad * 4;   // C rows for this lane (4 regs)

    // prefetch x tile: 16 dwords/thread (overlaps with LDS + MFMA)
    int xv[4][4];
    #pragma unroll
    for (int nb = 0; nb < 4; nb++) {
        int g = g0 + nb * 16 + ln;
        #pragma unroll
        for (int r = 0; r < 4; r++)
            xv[nb][r] = x[(brow0 + r) * Gn + g];
    }

    f32x4 acc[4];
    #pragma unroll
    for (int nb = 0; nb < 4; nb++) acc[nb] = (f32x4){0.f, 0.f, 0.f, 0.f};

    __syncthreads();

    // K=64 in two MFMA steps; wave handles m-block=wave, all 4 n-blocks
    #pragma unroll
    for (int kb = 0; kb < 2; kb++) {
        bf16x8 af = *(const bf16x8*)&sA[mrow][kb * 32 + quad * 8];
        #pragma unroll
        for (int nb = 0; nb < 4; nb++) {
            bf16x8 bf = *(const bf16x8*)&sB[nb * 16 + ln][kb * 32 + quad * 8];
            acc[nb] = __builtin_amdgcn_mfma_f32_16x16x32_bf16(af, bf, acc[nb], 0, 0, 0);
        }
    }

    float vvr[4];
    #pragma unroll
    for (int r = 0; r < 4; r++) vvr[r] = sv64[wave * 16 + quad * 4 + r];

    float rowpart[4] = {0.f, 0.f, 0.f, 0.f};
    #pragma unroll
    for (int nb = 0; nb < 4; nb++) {
        const float lspv = sLsp[nb * 16 + ln];
        const float lsnv = sLsn[nb * 16 + ln];
        const float ev   = sEps[nb * 16 + ln];
        #pragma unroll
        for (int r = 0; r < 4; r++) {
            const float rr = fmaf(ev, vvr[r], acc[nb][r]);   // + eps*v64, fp32
            const int   xi = xv[nb][r];
            const float xf = (float)xi;
            const float s  = rr + xf;
            // lgamma(s) - lgamma(rr), shift-4 Stirling (constants & -z cancel)
            const float wr = rr + 4.f, wx = s + 4.f;
            const float Pr = rr * (rr + 1.f) * ((rr + 2.f) * (rr + 3.f));
            const float Px = s  * (s  + 1.f) * ((s  + 2.f) * (s  + 3.f));
            const float lnQ = __logf(__fdividef(Px, Pr));
            float D = fmaf(wx - 0.5f, __logf(wx), -fmaf(wr - 0.5f, __logf(wr), xf))
                      - lnQ - 0.0833333333f * __fdividef(xf, wx * wr);
            float term = D - lfact[xi] + fmaf(xf, lspv, rr * lsnv);
            rowpart[r] += term;
        }
    }

    // reduce over the 16 gene-lanes of each quad, one atomic per row
    #pragma unroll
    for (int r = 0; r < 4; r++) {
        float v = rowpart[r];
        v += __shfl_xor(v, 1, 64);
        v += __shfl_xor(v, 2, 64);
        v += __shfl_xor(v, 4, 64);
        v += __shfl_xor(v, 8, 64);
        if (ln == 0) atomicAdd(&out[brow0 + r], -v);
    }
}

// ---------- launch ----------

extern "C" void kernel_launch(void* const* d_in, const int* in_sizes, int n_in,
                              void* d_out, int out_size, void* d_ws, size_t ws_size,
                              hipStream_t stream) {
    const int*   x     = (const int*)d_in[0];
    const int*   ind_x = (const int*)d_in[2];
    const float* W     = (const float*)d_in[3];
    const float* px_o  = (const float*)d_in[4];
    const float* eta   = (const float*)d_in[5];
    const float* V     = (const float*)d_in[6];
    const float* beta  = (const float*)d_in[7];
    float* out = (float*)d_out;

    // ws layout (bytes):
    char* wsb = (char*)d_ws;
    unsigned short* rhB = (unsigned short*)(wsb);                     // Gn*64*2 = 2,048,000
    unsigned short* vBg = (unsigned short*)(wsb + 2048000);           // Bn*64*2 =   524,288
    float*          v64 = (float*)(wsb + 2572288);                    // Bn*4    =    16,384
    float*          lsp = (float*)(wsb + 2588672);                    // Gn*4
    float*          lsn = (float*)(wsb + 2652672);
    float*          eps = (float*)(wsb + 2716672);

    hipMemsetAsync(d_out, 0, Bn * sizeof(float), stream);

    prep_genes<<<(Gn * 64) / 256, 256, 0, stream>>>(W, px_o, eta, beta, rhB, lsp, lsn, eps);
    prep_spots<<<(Bn * 64) / 256, 256, 0, stream>>>(V, ind_x, vBg, v64);
    prior_kernel<<<1, 256, 0, stream>>>(eta, out);

    dim3 grid(Gn / 64, Bn / 64);   // 250 x 64
    main_kernel<<<grid, 256, 0, stream>>>(x, rhB, vBg, v64, lsp, lsn, eps, out);
}